// Round 2
// baseline (2376.023 us; speedup 1.0000x reference)
//
#include <hip/hip_runtime.h>
#include <hip/hip_bf16.h>

#define N_IN   200000
#define N_OUT  600000
#define KOFF   27
#define PPAIR  150000
#define NPAIR  (KOFF * PPAIR)       // 4,050,000
#define C      96
#define BN_EPS 1e-5f

using bf16x8 = __attribute__((ext_vector_type(8))) __bf16;
using f32x4  = __attribute__((ext_vector_type(4))) float;

static __device__ __forceinline__ unsigned short f2b(float x) {
    __hip_bfloat16 h = __float2bfloat16(x);
    return *reinterpret_cast<unsigned short*>(&h);
}
static __device__ __forceinline__ float b2f(unsigned short u) {
    __hip_bfloat16 h = *reinterpret_cast<__hip_bfloat16*>(&u);
    return __bfloat162float(h);
}

// ---- feats fp32 -> bf16, 8 elems/thread. 19,200,000 = 9375*256*8 exactly.
__global__ void cvt_feats(const float* __restrict__ src, unsigned short* __restrict__ dst) {
    int t = blockIdx.x * 256 + threadIdx.x;
    const float4* s4 = (const float4*)src;
    float4 a = s4[2 * t], b = s4[2 * t + 1];
    union { unsigned short u[8]; uint4 v; } r;
    r.u[0] = f2b(a.x); r.u[1] = f2b(a.y); r.u[2] = f2b(a.z); r.u[3] = f2b(a.w);
    r.u[4] = f2b(b.x); r.u[5] = f2b(b.y); r.u[6] = f2b(b.z); r.u[7] = f2b(b.w);
    ((uint4*)dst)[t] = r.v;
}

// ---- weight [k][c_in][c_out] fp32 -> wt [k][c_out][c_in] bf16
__global__ void cvt_w(const float* __restrict__ w, unsigned short* __restrict__ wt) {
    int t = blockIdx.x * 256 + threadIdx.x;   // 972*256 = 248832 exactly
    int k = t / 9216;
    int rem = t - k * 9216;
    int o = rem / 96;
    int i = rem - o * 96;
    wt[t] = f2b(w[k * 9216 + i * 96 + o]);
}

// ---- Phase A: gather -> 64x96 @ 96x96 bf16 MFMA -> dense bf16 contrib rows (plain stores)
__global__ __launch_bounds__(256, 4) void contrib_k(
    const unsigned short* __restrict__ fb,   // feats bf16 [N_IN][96]
    const unsigned short* __restrict__ wt,   // weight bf16 [27][96(out)][96(in)]
    const int* __restrict__ in_idx,
    unsigned short* __restrict__ contrib)    // [NPAIR][96] bf16
{
    __shared__ unsigned short As[64][104];   // 96->104 pad: 2-way bank alias = free
    __shared__ unsigned short Bs[96][104];

    const int t    = threadIdx.x;
    const int k    = blockIdx.y;
    const int row0 = blockIdx.x * 64;
    const long kp  = (long)k * PPAIR;

    for (int i = t; i < 64 * 12; i += 256) {
        int row = i / 12, ch = i - row * 12;
        int p = row0 + row; if (p >= PPAIR) p = PPAIR - 1;
        int g = in_idx[kp + p];
        *(uint4*)(&As[row][ch * 8]) = *(const uint4*)(fb + (size_t)g * 96 + ch * 8);
    }
    {
        const uint4* wsrc = (const uint4*)(wt + (size_t)k * 9216);
        for (int i = t; i < 96 * 12; i += 256) {
            int row = i / 12, ch = i - row * 12;
            *(uint4*)(&Bs[row][ch * 8]) = wsrc[row * 12 + ch];
        }
    }
    __syncthreads();

    const int wave = t >> 6, lane = t & 63;
    const int quad = lane >> 4, l16 = lane & 15;
    const int mrow = wave * 16 + l16;

    f32x4 acc[6];
#pragma unroll
    for (int n = 0; n < 6; n++) acc[n] = (f32x4){0.f, 0.f, 0.f, 0.f};

#pragma unroll
    for (int kk = 0; kk < 3; kk++) {
        int kb = kk * 32 + quad * 8;
        bf16x8 a = *(const bf16x8*)(&As[mrow][kb]);
#pragma unroll
        for (int n = 0; n < 6; n++) {
            bf16x8 b = *(const bf16x8*)(&Bs[n * 16 + l16][kb]);
            acc[n] = __builtin_amdgcn_mfma_f32_16x16x32_bf16(a, b, acc[n], 0, 0, 0);
        }
    }

    // D layout: col = n*16 + l16, row(within tile) = quad*4 + r
#pragma unroll
    for (int r = 0; r < 4; r++) {
        int lr = wave * 16 + quad * 4 + r;
        int p = row0 + lr;
        if (p < PPAIR) {
            unsigned short* crow = contrib + (size_t)(kp + p) * 96;
#pragma unroll
            for (int n = 0; n < 6; n++)
                crow[n * 16 + l16] = f2b(acc[n][r]);
        }
    }
}

// ---- counting sort of out_idx --------------------------------------------
__global__ void k_hist(const int* __restrict__ out_idx, int* __restrict__ counts) {
    int t = blockIdx.x * 256 + threadIdx.x;
    if (t < NPAIR) atomicAdd(&counts[out_idx[t]], 1);
}

// per-1024-chunk sums (586 blocks)
__global__ void k_bsum(const int* __restrict__ counts, int* __restrict__ bsum) {
    __shared__ int ls[256];
    int b = blockIdx.x, t = threadIdx.x;
    int base = b * 1024 + t * 4;
    int s = 0;
#pragma unroll
    for (int j = 0; j < 4; j++) { int i = base + j; if (i < N_OUT) s += counts[i]; }
    ls[t] = s;
    __syncthreads();
    for (int off = 128; off > 0; off >>= 1) {
        if (t < off) ls[t] += ls[t + off];
        __syncthreads();
    }
    if (t == 0) bsum[b] = ls[0];
}

// exclusive scan of 586 block sums (1 block of 1024)
__global__ void k_scan_bsum(const int* __restrict__ bsum, int* __restrict__ bsum_ex) {
    __shared__ int sc[1024];
    int t = threadIdx.x;
    int v = (t < 586) ? bsum[t] : 0;
    sc[t] = v;
    __syncthreads();
    for (int off = 1; off < 1024; off <<= 1) {
        int add = (t >= off) ? sc[t - off] : 0;
        __syncthreads();
        sc[t] += add;
        __syncthreads();
    }
    bsum_ex[t] = sc[t] - v;   // exclusive
}

// local scan within each 1024-chunk -> csr (exclusive prefix over all counts)
__global__ void k_scan_local(const int* __restrict__ counts, const int* __restrict__ bsum_ex,
                             int* __restrict__ csr) {
    __shared__ int sc[256];
    int b = blockIdx.x, t = threadIdx.x;
    int base = b * 1024 + t * 4;
    int c[4];
    int s = 0;
#pragma unroll
    for (int j = 0; j < 4; j++) {
        int i = base + j;
        c[j] = (i < N_OUT) ? counts[i] : 0;
        s += c[j];
    }
    sc[t] = s;
    __syncthreads();
    for (int off = 1; off < 256; off <<= 1) {
        int add = (t >= off) ? sc[t - off] : 0;
        __syncthreads();
        sc[t] += add;
        __syncthreads();
    }
    int run = bsum_ex[b] + sc[t] - s;   // exclusive within-grid prefix
#pragma unroll
    for (int j = 0; j < 4; j++) {
        int i = base + j;
        if (i < N_OUT) {
            csr[i] = run;
            run += c[j];
            if (i == N_OUT - 1) csr[N_OUT] = run;
        }
    }
}

__global__ void k_perm(const int* __restrict__ out_idx, int* __restrict__ cursor,
                       int* __restrict__ perm) {
    int t = blockIdx.x * 256 + threadIdx.x;
    if (t < NPAIR) {
        int o = out_idx[t];
        int pos = atomicAdd(&cursor[o], 1);
        perm[pos] = t;
    }
}

// ---- Phase B: owner-computes reduction + fused BN stats ------------------
// block = 384 threads: rl = t/96 in [0,4), c = t%96. Grid-stride over row-groups of 4.
__global__ __launch_bounds__(384) void reduce_bn(
    const unsigned short* __restrict__ contrib,
    const int* __restrict__ csr,
    const int* __restrict__ perm,
    float* __restrict__ out,
    float* __restrict__ sums)
{
    __shared__ float lsum[96], lq[96];
    int t = threadIdx.x;
    int rl = t / 96, c = t - rl * 96;
    float psum = 0.f, pq = 0.f;

    for (int rb = blockIdx.x * 4; rb < N_OUT; rb += gridDim.x * 4) {
        int r = rb + rl;
        if (r < N_OUT) {
            int s = csr[r], e = csr[r + 1];
            float acc = 0.f;
            for (int j = s; j < e; j++) {
                int eid = perm[j];
                acc += b2f(contrib[(size_t)eid * 96 + c]);
            }
            out[(size_t)r * 96 + c] = acc;
            psum += acc;
            pq += acc * acc;
        }
    }

    if (t < 96) { lsum[t] = 0.f; lq[t] = 0.f; }
    __syncthreads();
    atomicAdd(&lsum[c], psum);
    atomicAdd(&lq[c], pq);
    __syncthreads();
    if (t < 96) {
        atomicAdd(&sums[t], lsum[t]);
        atomicAdd(&sums[96 + t], lq[t]);
    }
}

// sums[0..95] -> scale, sums[96..191] -> shift
__global__ void bn_final(float* __restrict__ sums, const float* __restrict__ gamma,
                         const float* __restrict__ beta) {
    int c = threadIdx.x;
    if (c < 96) {
        float mean = sums[c] * (1.0f / (float)N_OUT);
        float var  = sums[96 + c] * (1.0f / (float)N_OUT) - mean * mean;
        float inv  = rsqrtf(var + BN_EPS);
        float sc   = inv * gamma[c];
        sums[c]      = sc;
        sums[96 + c] = beta[c] - mean * sc;
    }
}

__global__ void bn_apply(float* __restrict__ out, const float* __restrict__ sums) {
    int t = blockIdx.x * 256 + threadIdx.x;
    int g = t % 24;
    float sc0 = sums[g * 4 + 0], sc1 = sums[g * 4 + 1];
    float sc2 = sums[g * 4 + 2], sc3 = sums[g * 4 + 3];
    float sh0 = sums[96 + g * 4 + 0], sh1 = sums[96 + g * 4 + 1];
    float sh2 = sums[96 + g * 4 + 2], sh3 = sums[96 + g * 4 + 3];
    float4* o4 = (float4*)out;
    for (long f = t; f < 14400000L; f += 258048) {
        float4 v = o4[f];
        v.x = fmaxf(v.x * sc0 + sh0, 0.f);
        v.y = fmaxf(v.y * sc1 + sh1, 0.f);
        v.z = fmaxf(v.z * sc2 + sh2, 0.f);
        v.w = fmaxf(v.w * sc3 + sh3, 0.f);
        o4[f] = v;
    }
}

extern "C" void kernel_launch(void* const* d_in, const int* in_sizes, int n_in,
                              void* d_out, int out_size, void* d_ws, size_t ws_size,
                              hipStream_t stream) {
    const float* feats  = (const float*)d_in[0];
    const int* in_idx   = (const int*)d_in[1];
    const int* out_idx  = (const int*)d_in[2];
    const float* weight = (const float*)d_in[3];
    const float* gamma  = (const float*)d_in[4];
    const float* beta   = (const float*)d_in[5];
    float* out = (float*)d_out;

    char* ws = (char*)d_ws;
    size_t off = 0;
    unsigned short* fb      = (unsigned short*)(ws + off); off += 38400000;          // feats bf16
    unsigned short* wt      = (unsigned short*)(ws + off); off += 497664;            // weight^T bf16
    unsigned short* contrib = (unsigned short*)(ws + off); off += (size_t)NPAIR * 96 * 2; // 777.6 MB
    int* counts             = (int*)(ws + off); off += 2400000;
    int* csr                = (int*)(ws + off); off += 2400016;
    int* cursor             = (int*)(ws + off); off += 2400016;
    int* bsum               = (int*)(ws + off); off += 4096;
    int* bsum_ex            = (int*)(ws + off); off += 4096;
    int* perm               = (int*)(ws + off); off += (size_t)NPAIR * 4;            // 16.2 MB
    float* sums             = (float*)(ws + off); off += 768;

    hipMemsetAsync(counts, 0, (size_t)N_OUT * sizeof(int), stream);
    hipMemsetAsync(sums, 0, 192 * sizeof(float), stream);

    cvt_feats<<<9375, 256, 0, stream>>>(feats, fb);
    cvt_w<<<972, 256, 0, stream>>>(weight, wt);

    // sort prep (overlappable with contrib compute order on same stream; serialized is fine)
    k_hist<<<(NPAIR + 255) / 256, 256, 0, stream>>>(out_idx, counts);
    k_bsum<<<586, 256, 0, stream>>>(counts, bsum);
    k_scan_bsum<<<1, 1024, 0, stream>>>(bsum, bsum_ex);
    k_scan_local<<<586, 256, 0, stream>>>(counts, bsum_ex, csr);
    hipMemcpyAsync(cursor, csr, (size_t)N_OUT * sizeof(int), hipMemcpyDeviceToDevice, stream);
    k_perm<<<(NPAIR + 255) / 256, 256, 0, stream>>>(out_idx, cursor, perm);

    contrib_k<<<dim3(2344, KOFF), 256, 0, stream>>>(fb, wt, in_idx, contrib);

    reduce_bn<<<1024, 384, 0, stream>>>(contrib, csr, perm, out, sums);
    bn_final<<<1, 128, 0, stream>>>(sums, gamma, beta);
    bn_apply<<<1008, 256, 0, stream>>>(out, sums);
}

// Round 3
// 1618.367 us; speedup vs baseline: 1.4682x; 1.4682x over previous
//
#include <hip/hip_runtime.h>
#include <hip/hip_bf16.h>

#define N_IN   200000
#define N_OUT  600000
#define KOFF   27
#define PPAIR  150000
#define NPAIR  (KOFF * PPAIR)       // 4,050,000
#define C      96
#define BN_EPS 1e-5f

using bf16x8 = __attribute__((ext_vector_type(8))) __bf16;
using f32x4  = __attribute__((ext_vector_type(4))) float;

static __device__ __forceinline__ unsigned short f2b(float x) {
    __hip_bfloat16 h = __float2bfloat16(x);
    return *reinterpret_cast<unsigned short*>(&h);
}

// ---- feats fp32 -> bf16, 8 elems/thread. 19,200,000 = 9375*256*8 exactly.
__global__ void cvt_feats(const float* __restrict__ src, unsigned short* __restrict__ dst) {
    int t = blockIdx.x * 256 + threadIdx.x;
    const float4* s4 = (const float4*)src;
    float4 a = s4[2 * t], b = s4[2 * t + 1];
    union { unsigned short u[8]; uint4 v; } r;
    r.u[0] = f2b(a.x); r.u[1] = f2b(a.y); r.u[2] = f2b(a.z); r.u[3] = f2b(a.w);
    r.u[4] = f2b(b.x); r.u[5] = f2b(b.y); r.u[6] = f2b(b.z); r.u[7] = f2b(b.w);
    ((uint4*)dst)[t] = r.v;
}

// ---- weight [k][c_in][c_out] fp32 -> wt [k][c_out][c_in] bf16
__global__ void cvt_w(const float* __restrict__ w, unsigned short* __restrict__ wt) {
    int t = blockIdx.x * 256 + threadIdx.x;   // 972*256 = 248832 exactly
    int k = t / 9216;
    int rem = t - k * 9216;
    int o = rem / 96;
    int i = rem - o * 96;
    wt[t] = f2b(w[k * 9216 + i * 96 + o]);
}

// ---- counting sort of out_idx --------------------------------------------
__global__ void k_hist(const int* __restrict__ out_idx, int* __restrict__ counts) {
    int t = blockIdx.x * 256 + threadIdx.x;
    if (t < NPAIR) atomicAdd(&counts[out_idx[t]], 1);
}

__global__ void k_bsum(const int* __restrict__ counts, int* __restrict__ bsum) {
    __shared__ int ls[256];
    int b = blockIdx.x, t = threadIdx.x;
    int base = b * 1024 + t * 4;
    int s = 0;
#pragma unroll
    for (int j = 0; j < 4; j++) { int i = base + j; if (i < N_OUT) s += counts[i]; }
    ls[t] = s;
    __syncthreads();
    for (int off = 128; off > 0; off >>= 1) {
        if (t < off) ls[t] += ls[t + off];
        __syncthreads();
    }
    if (t == 0) bsum[b] = ls[0];
}

__global__ void k_scan_bsum(const int* __restrict__ bsum, int* __restrict__ bsum_ex) {
    __shared__ int sc[1024];
    int t = threadIdx.x;
    int v = (t < 586) ? bsum[t] : 0;
    sc[t] = v;
    __syncthreads();
    for (int off = 1; off < 1024; off <<= 1) {
        int add = (t >= off) ? sc[t - off] : 0;
        __syncthreads();
        sc[t] += add;
        __syncthreads();
    }
    bsum_ex[t] = sc[t] - v;   // exclusive
}

__global__ void k_scan_local(const int* __restrict__ counts, const int* __restrict__ bsum_ex,
                             int* __restrict__ csr) {
    __shared__ int sc[256];
    int b = blockIdx.x, t = threadIdx.x;
    int base = b * 1024 + t * 4;
    int c[4];
    int s = 0;
#pragma unroll
    for (int j = 0; j < 4; j++) {
        int i = base + j;
        c[j] = (i < N_OUT) ? counts[i] : 0;
        s += c[j];
    }
    sc[t] = s;
    __syncthreads();
    for (int off = 1; off < 256; off <<= 1) {
        int add = (t >= off) ? sc[t - off] : 0;
        __syncthreads();
        sc[t] += add;
        __syncthreads();
    }
    int run = bsum_ex[b] + sc[t] - s;
#pragma unroll
    for (int j = 0; j < 4; j++) {
        int i = base + j;
        if (i < N_OUT) {
            csr[i] = run;
            run += c[j];
            if (i == N_OUT - 1) csr[N_OUT] = run;
        }
    }
}

// rank[e] = final position of pair e in out-sorted order
__global__ void k_rank(const int* __restrict__ out_idx, int* __restrict__ cursor,
                       int* __restrict__ rank) {
    int t = blockIdx.x * 256 + threadIdx.x;
    if (t < NPAIR) {
        int o = out_idx[t];
        rank[t] = atomicAdd(&cursor[o], 1);
    }
}

// ---- Phase A: gather -> 64x96 @ 96x96 bf16 MFMA -> scatter rows to SORTED slots
__global__ __launch_bounds__(256, 4) void contrib_k(
    const unsigned short* __restrict__ fb,   // feats bf16 [N_IN][96]
    const unsigned short* __restrict__ wt,   // weight bf16 [27][96(out)][96(in)]
    const int* __restrict__ in_idx,
    const int* __restrict__ rank,
    unsigned short* __restrict__ contrib)    // [NPAIR][96] bf16, sorted by out_idx
{
    __shared__ unsigned short As[64][104];
    __shared__ unsigned short Bs[96][104];
    __shared__ int s_rank[64];

    const int t    = threadIdx.x;
    const int k    = blockIdx.y;
    const int row0 = blockIdx.x * 64;
    const long kp  = (long)k * PPAIR;

    if (t < 64) {
        int p = row0 + t;
        s_rank[t] = (p < PPAIR) ? rank[kp + p] : -1;
    }
    for (int i = t; i < 64 * 12; i += 256) {
        int row = i / 12, ch = i - row * 12;
        int p = row0 + row; if (p >= PPAIR) p = PPAIR - 1;
        int g = in_idx[kp + p];
        *(uint4*)(&As[row][ch * 8]) = *(const uint4*)(fb + (size_t)g * 96 + ch * 8);
    }
    {
        const uint4* wsrc = (const uint4*)(wt + (size_t)k * 9216);
        for (int i = t; i < 96 * 12; i += 256) {
            int row = i / 12, ch = i - row * 12;
            *(uint4*)(&Bs[row][ch * 8]) = wsrc[row * 12 + ch];
        }
    }
    __syncthreads();

    const int wave = t >> 6, lane = t & 63;
    const int quad = lane >> 4, l16 = lane & 15;
    const int mrow = wave * 16 + l16;

    f32x4 acc[6];
#pragma unroll
    for (int n = 0; n < 6; n++) acc[n] = (f32x4){0.f, 0.f, 0.f, 0.f};

#pragma unroll
    for (int kk = 0; kk < 3; kk++) {
        int kb = kk * 32 + quad * 8;
        bf16x8 a = *(const bf16x8*)(&As[mrow][kb]);
#pragma unroll
        for (int n = 0; n < 6; n++) {
            bf16x8 b = *(const bf16x8*)(&Bs[n * 16 + l16][kb]);
            acc[n] = __builtin_amdgcn_mfma_f32_16x16x32_bf16(a, b, acc[n], 0, 0, 0);
        }
    }

    // D layout: col = n*16 + l16, row(within tile) = quad*4 + r. Store to sorted slot.
#pragma unroll
    for (int r = 0; r < 4; r++) {
        int lr = wave * 16 + quad * 4 + r;
        int rk = s_rank[lr];
        if (rk >= 0) {
            unsigned short* crow = contrib + (size_t)rk * 96;
#pragma unroll
            for (int n = 0; n < 6; n++)
                crow[n * 16 + l16] = f2b(acc[n][r]);
        }
    }
}

// ---- Phase B: sequential-slab reduction + fused BN stats ------------------
// block 384: rl = t/48 in [0,8) rows in flight, c2 = t%48 channel-pair.
__global__ __launch_bounds__(384) void reduce_bn(
    const unsigned short* __restrict__ contrib,
    const int* __restrict__ csr,
    float* __restrict__ out,
    float* __restrict__ sums)
{
    __shared__ float lsum[96], lq[96];
    int t = threadIdx.x;
    int rl = t / 48, c2 = t - rl * 48;
    float ps0 = 0.f, ps1 = 0.f, pq0 = 0.f, pq1 = 0.f;

    for (int rb = blockIdx.x * 8; rb < N_OUT; rb += gridDim.x * 8) {
        int r = rb + rl;                       // N_OUT % 8 == 0, always in range
        int s = csr[r], e = csr[r + 1];
        float acc0 = 0.f, acc1 = 0.f;
        for (int j = s; j < e; j++) {
            unsigned int u = *(const unsigned int*)(contrib + (size_t)j * 96 + c2 * 2);
            acc0 += __uint_as_float(u << 16);
            acc1 += __uint_as_float(u & 0xffff0000u);
        }
        *(float2*)(out + (size_t)r * 96 + c2 * 2) = make_float2(acc0, acc1);
        ps0 += acc0; ps1 += acc1;
        pq0 += acc0 * acc0; pq1 += acc1 * acc1;
    }

    if (t < 96) { lsum[t] = 0.f; lq[t] = 0.f; }
    __syncthreads();
    atomicAdd(&lsum[c2 * 2 + 0], ps0); atomicAdd(&lsum[c2 * 2 + 1], ps1);
    atomicAdd(&lq[c2 * 2 + 0], pq0);   atomicAdd(&lq[c2 * 2 + 1], pq1);
    __syncthreads();
    if (t < 96) {
        atomicAdd(&sums[t], lsum[t]);
        atomicAdd(&sums[96 + t], lq[t]);
    }
}

__global__ void bn_final(float* __restrict__ sums, const float* __restrict__ gamma,
                         const float* __restrict__ beta) {
    int c = threadIdx.x;
    if (c < 96) {
        float mean = sums[c] * (1.0f / (float)N_OUT);
        float var  = sums[96 + c] * (1.0f / (float)N_OUT) - mean * mean;
        float inv  = rsqrtf(var + BN_EPS);
        float sc   = inv * gamma[c];
        sums[c]      = sc;
        sums[96 + c] = beta[c] - mean * sc;
    }
}

__global__ void bn_apply(float* __restrict__ out, const float* __restrict__ sums) {
    int t = blockIdx.x * 256 + threadIdx.x;
    int g = t % 24;
    float sc0 = sums[g * 4 + 0], sc1 = sums[g * 4 + 1];
    float sc2 = sums[g * 4 + 2], sc3 = sums[g * 4 + 3];
    float sh0 = sums[96 + g * 4 + 0], sh1 = sums[96 + g * 4 + 1];
    float sh2 = sums[96 + g * 4 + 2], sh3 = sums[96 + g * 4 + 3];
    float4* o4 = (float4*)out;
    for (long f = t; f < 14400000L; f += 258048) {
        float4 v = o4[f];
        v.x = fmaxf(v.x * sc0 + sh0, 0.f);
        v.y = fmaxf(v.y * sc1 + sh1, 0.f);
        v.z = fmaxf(v.z * sc2 + sh2, 0.f);
        v.w = fmaxf(v.w * sc3 + sh3, 0.f);
        o4[f] = v;
    }
}

extern "C" void kernel_launch(void* const* d_in, const int* in_sizes, int n_in,
                              void* d_out, int out_size, void* d_ws, size_t ws_size,
                              hipStream_t stream) {
    const float* feats  = (const float*)d_in[0];
    const int* in_idx   = (const int*)d_in[1];
    const int* out_idx  = (const int*)d_in[2];
    const float* weight = (const float*)d_in[3];
    const float* gamma  = (const float*)d_in[4];
    const float* beta   = (const float*)d_in[5];
    float* out = (float*)d_out;

    char* ws = (char*)d_ws;
    size_t off = 0;
    unsigned short* fb      = (unsigned short*)(ws + off); off += 38400000;
    unsigned short* wt      = (unsigned short*)(ws + off); off += 497664;
    unsigned short* contrib = (unsigned short*)(ws + off); off += (size_t)NPAIR * 96 * 2;
    int* counts             = (int*)(ws + off); off += 2400000;
    int* csr                = (int*)(ws + off); off += 2400016;
    int* cursor             = (int*)(ws + off); off += 2400016;
    int* bsum               = (int*)(ws + off); off += 4096;
    int* bsum_ex            = (int*)(ws + off); off += 4096;
    int* rank               = (int*)(ws + off); off += (size_t)NPAIR * 4;
    float* sums             = (float*)(ws + off); off += 768;

    hipMemsetAsync(counts, 0, (size_t)N_OUT * sizeof(int), stream);
    hipMemsetAsync(sums, 0, 192 * sizeof(float), stream);

    cvt_feats<<<9375, 256, 0, stream>>>(feats, fb);
    cvt_w<<<972, 256, 0, stream>>>(weight, wt);

    k_hist<<<(NPAIR + 255) / 256, 256, 0, stream>>>(out_idx, counts);
    k_bsum<<<586, 256, 0, stream>>>(counts, bsum);
    k_scan_bsum<<<1, 1024, 0, stream>>>(bsum, bsum_ex);
    k_scan_local<<<586, 256, 0, stream>>>(counts, bsum_ex, csr);
    hipMemcpyAsync(cursor, csr, (size_t)N_OUT * sizeof(int), hipMemcpyDeviceToDevice, stream);
    k_rank<<<(NPAIR + 255) / 256, 256, 0, stream>>>(out_idx, cursor, rank);

    contrib_k<<<dim3(2344, KOFF), 256, 0, stream>>>(fb, wt, in_idx, rank, contrib);

    reduce_bn<<<2048, 384, 0, stream>>>(contrib, csr, out, sums);
    bn_final<<<1, 128, 0, stream>>>(sums, gamma, beta);
    bn_apply<<<1008, 256, 0, stream>>>(out, sums);
}

// Round 4
// 1575.290 us; speedup vs baseline: 1.5083x; 1.0273x over previous
//
#include <hip/hip_runtime.h>
#include <hip/hip_bf16.h>

#define N_IN   200000
#define N_OUT  600000
#define KOFF   27
#define PPAIR  150000
#define NPAIR  (KOFF * PPAIR)       // 4,050,000
#define C      96
#define BN_EPS 1e-5f

using bf16x8 = __attribute__((ext_vector_type(8))) __bf16;
using f32x4  = __attribute__((ext_vector_type(4))) float;

static __device__ __forceinline__ unsigned short f2b(float x) {
    __hip_bfloat16 h = __float2bfloat16(x);
    return *reinterpret_cast<unsigned short*>(&h);
}
static __device__ __forceinline__ float b_lo(unsigned int u) { return __uint_as_float(u << 16); }
static __device__ __forceinline__ float b_hi(unsigned int u) { return __uint_as_float(u & 0xffff0000u); }

// ---- feats fp32 -> bf16, 8 elems/thread. 19,200,000 = 9375*256*8 exactly.
__global__ void cvt_feats(const float* __restrict__ src, unsigned short* __restrict__ dst) {
    int t = blockIdx.x * 256 + threadIdx.x;
    const float4* s4 = (const float4*)src;
    float4 a = s4[2 * t], b = s4[2 * t + 1];
    union { unsigned short u[8]; uint4 v; } r;
    r.u[0] = f2b(a.x); r.u[1] = f2b(a.y); r.u[2] = f2b(a.z); r.u[3] = f2b(a.w);
    r.u[4] = f2b(b.x); r.u[5] = f2b(b.y); r.u[6] = f2b(b.z); r.u[7] = f2b(b.w);
    ((uint4*)dst)[t] = r.v;
}

// ---- weight [k][c_in][c_out] fp32 -> wt [k][c_out][c_in] bf16
__global__ void cvt_w(const float* __restrict__ w, unsigned short* __restrict__ wt) {
    int t = blockIdx.x * 256 + threadIdx.x;   // 972*256 = 248832 exactly
    int k = t / 9216;
    int rem = t - k * 9216;
    int o = rem / 96;
    int i = rem - o * 96;
    wt[t] = f2b(w[k * 9216 + i * 96 + o]);
}

// ---- counting sort of out_idx --------------------------------------------
__global__ void k_hist(const int* __restrict__ out_idx, int* __restrict__ counts) {
    int t = blockIdx.x * 256 + threadIdx.x;
    if (t < NPAIR) atomicAdd(&counts[out_idx[t]], 1);
}

__global__ void k_bsum(const int* __restrict__ counts, int* __restrict__ bsum) {
    __shared__ int ls[256];
    int b = blockIdx.x, t = threadIdx.x;
    int base = b * 1024 + t * 4;
    int s = 0;
#pragma unroll
    for (int j = 0; j < 4; j++) { int i = base + j; if (i < N_OUT) s += counts[i]; }
    ls[t] = s;
    __syncthreads();
    for (int off = 128; off > 0; off >>= 1) {
        if (t < off) ls[t] += ls[t + off];
        __syncthreads();
    }
    if (t == 0) bsum[b] = ls[0];
}

__global__ void k_scan_bsum(const int* __restrict__ bsum, int* __restrict__ bsum_ex) {
    __shared__ int sc[1024];
    int t = threadIdx.x;
    int v = (t < 586) ? bsum[t] : 0;
    sc[t] = v;
    __syncthreads();
    for (int off = 1; off < 1024; off <<= 1) {
        int add = (t >= off) ? sc[t - off] : 0;
        __syncthreads();
        sc[t] += add;
        __syncthreads();
    }
    bsum_ex[t] = sc[t] - v;   // exclusive
}

__global__ void k_scan_local(const int* __restrict__ counts, const int* __restrict__ bsum_ex,
                             int* __restrict__ csr) {
    __shared__ int sc[256];
    int b = blockIdx.x, t = threadIdx.x;
    int base = b * 1024 + t * 4;
    int c[4];
    int s = 0;
#pragma unroll
    for (int j = 0; j < 4; j++) {
        int i = base + j;
        c[j] = (i < N_OUT) ? counts[i] : 0;
        s += c[j];
    }
    sc[t] = s;
    __syncthreads();
    for (int off = 1; off < 256; off <<= 1) {
        int add = (t >= off) ? sc[t - off] : 0;
        __syncthreads();
        sc[t] += add;
        __syncthreads();
    }
    int run = bsum_ex[b] + sc[t] - s;
#pragma unroll
    for (int j = 0; j < 4; j++) {
        int i = base + j;
        if (i < N_OUT) {
            csr[i] = run;
            run += c[j];
            if (i == N_OUT - 1) csr[N_OUT] = run;
        }
    }
}

__global__ void k_rank(const int* __restrict__ out_idx, int* __restrict__ cursor,
                       int* __restrict__ rank) {
    int t = blockIdx.x * 256 + threadIdx.x;
    if (t < NPAIR) {
        int o = out_idx[t];
        rank[t] = atomicAdd(&cursor[o], 1);
    }
}

// ---- Phase A: direct-global gather -> MFMA -> LDS repack -> uint4 scatter to sorted slots
__global__ __launch_bounds__(256, 6) void contrib_k(
    const unsigned short* __restrict__ fb,   // feats bf16 [N_IN][96]
    const unsigned short* __restrict__ wt,   // weight bf16 [27][96(out)][96(in)]
    const int* __restrict__ in_idx,
    const int* __restrict__ rank,
    unsigned short* __restrict__ contrib)    // [NPAIR][96] bf16, sorted by out_idx
{
    __shared__ int s_g[64];
    __shared__ int s_rank[64];
    __shared__ __align__(16) unsigned short Ds[4][16 * 104];  // per-wave D tile, stride 104

    const int t    = threadIdx.x;
    const int k    = blockIdx.y;
    const int row0 = blockIdx.x * 64;
    const long kp  = (long)k * PPAIR;

    if (t < 64) {
        int p  = row0 + t;
        int pc = (p < PPAIR) ? p : (PPAIR - 1);
        s_g[t]    = in_idx[kp + pc];
        s_rank[t] = (p < PPAIR) ? rank[kp + p] : -1;
    }
    __syncthreads();

    const int wave = t >> 6, lane = t & 63;
    const int quad = lane >> 4, l16 = lane & 15;
    const int mrow = wave * 16 + l16;

    const unsigned short* arow = fb + (size_t)s_g[mrow] * 96 + quad * 8;
    const unsigned short* bbase = wt + (size_t)k * 9216 + l16 * 96 + quad * 8;

    f32x4 acc[6];
#pragma unroll
    for (int n = 0; n < 6; n++) acc[n] = (f32x4){0.f, 0.f, 0.f, 0.f};

#pragma unroll
    for (int kk = 0; kk < 3; kk++) {
        bf16x8 a = *(const bf16x8*)(arow + kk * 32);
#pragma unroll
        for (int n = 0; n < 6; n++) {
            bf16x8 b = *(const bf16x8*)(bbase + n * 16 * 96 + kk * 32);
            acc[n] = __builtin_amdgcn_mfma_f32_16x16x32_bf16(a, b, acc[n], 0, 0, 0);
        }
    }

    // Repack D tile via LDS: place hardware row (quad*4+r) at permuted slot (r*4+quad)
    // so the 4 quads of a ds_write_b16 land on distinct bank octets (stride 52 words).
    unsigned short* dw = &Ds[wave][0];
#pragma unroll
    for (int r = 0; r < 4; r++) {
        int prow = r * 4 + quad;
#pragma unroll
        for (int n = 0; n < 6; n++)
            dw[prow * 104 + n * 16 + l16] = f2b(acc[n][r]);
    }
    __syncthreads();

    // 3 x uint4 stores per lane: chunk q = s*64+lane; permuted row' = q/12, chunk-in-row = q%12
#pragma unroll
    for (int s = 0; s < 3; s++) {
        int q = s * 64 + lane;
        int prow = q / 12, ci = q - prow * 12;
        int orig = ((prow & 3) << 2) | (prow >> 2);   // invert the placement permutation
        int rk = s_rank[wave * 16 + orig];
        if (rk >= 0) {
            uint4 v = *(const uint4*)(dw + prow * 104 + ci * 8);
            *(uint4*)(contrib + (size_t)rk * 96 + ci * 8) = v;
        }
    }
}

// ---- Phase B: sequential-slab reduction + fused BN stats ------------------
// block 384: rl = t/24 in [0,16) rows in flight, c4 = t%24 -> 4 channels/lane.
__global__ __launch_bounds__(384) void reduce_bn(
    const unsigned short* __restrict__ contrib,
    const int* __restrict__ csr,
    float* __restrict__ out,
    float* __restrict__ sums)
{
    __shared__ float lsum[96], lq[96];
    int t = threadIdx.x;
    int rl = t / 24, c4 = t - rl * 24;
    float ps0 = 0.f, ps1 = 0.f, ps2 = 0.f, ps3 = 0.f;
    float pq0 = 0.f, pq1 = 0.f, pq2 = 0.f, pq3 = 0.f;

    for (int rb = blockIdx.x * 16; rb < N_OUT; rb += gridDim.x * 16) {
        int r = rb + rl;                       // N_OUT % 16 == 0
        int s = csr[r], e = csr[r + 1];
        float a0 = 0.f, a1 = 0.f, a2 = 0.f, a3 = 0.f;
        int j = s;
        for (; j + 1 < e; j += 2) {
            uint2 u = *(const uint2*)(contrib + (size_t)j * 96 + c4 * 4);
            uint2 v = *(const uint2*)(contrib + (size_t)(j + 1) * 96 + c4 * 4);
            a0 += b_lo(u.x); a1 += b_hi(u.x); a2 += b_lo(u.y); a3 += b_hi(u.y);
            a0 += b_lo(v.x); a1 += b_hi(v.x); a2 += b_lo(v.y); a3 += b_hi(v.y);
        }
        if (j < e) {
            uint2 u = *(const uint2*)(contrib + (size_t)j * 96 + c4 * 4);
            a0 += b_lo(u.x); a1 += b_hi(u.x); a2 += b_lo(u.y); a3 += b_hi(u.y);
        }
        *(float4*)(out + (size_t)r * 96 + c4 * 4) = make_float4(a0, a1, a2, a3);
        ps0 += a0; ps1 += a1; ps2 += a2; ps3 += a3;
        pq0 += a0 * a0; pq1 += a1 * a1; pq2 += a2 * a2; pq3 += a3 * a3;
    }

    if (t < 96) { lsum[t] = 0.f; lq[t] = 0.f; }
    __syncthreads();
    atomicAdd(&lsum[c4 * 4 + 0], ps0); atomicAdd(&lsum[c4 * 4 + 1], ps1);
    atomicAdd(&lsum[c4 * 4 + 2], ps2); atomicAdd(&lsum[c4 * 4 + 3], ps3);
    atomicAdd(&lq[c4 * 4 + 0], pq0);   atomicAdd(&lq[c4 * 4 + 1], pq1);
    atomicAdd(&lq[c4 * 4 + 2], pq2);   atomicAdd(&lq[c4 * 4 + 3], pq3);
    __syncthreads();
    if (t < 96) {
        atomicAdd(&sums[t], lsum[t]);
        atomicAdd(&sums[96 + t], lq[t]);
    }
}

__global__ void bn_final(float* __restrict__ sums, const float* __restrict__ gamma,
                         const float* __restrict__ beta) {
    int c = threadIdx.x;
    if (c < 96) {
        float mean = sums[c] * (1.0f / (float)N_OUT);
        float var  = sums[96 + c] * (1.0f / (float)N_OUT) - mean * mean;
        float inv  = rsqrtf(var + BN_EPS);
        float sc   = inv * gamma[c];
        sums[c]      = sc;
        sums[96 + c] = beta[c] - mean * sc;
    }
}

__global__ void bn_apply(float* __restrict__ out, const float* __restrict__ sums) {
    int t = blockIdx.x * 256 + threadIdx.x;
    int g = t % 24;
    float sc0 = sums[g * 4 + 0], sc1 = sums[g * 4 + 1];
    float sc2 = sums[g * 4 + 2], sc3 = sums[g * 4 + 3];
    float sh0 = sums[96 + g * 4 + 0], sh1 = sums[96 + g * 4 + 1];
    float sh2 = sums[96 + g * 4 + 2], sh3 = sums[96 + g * 4 + 3];
    float4* o4 = (float4*)out;
    for (long f = t; f < 14400000L; f += 258048) {
        float4 v = o4[f];
        v.x = fmaxf(v.x * sc0 + sh0, 0.f);
        v.y = fmaxf(v.y * sc1 + sh1, 0.f);
        v.z = fmaxf(v.z * sc2 + sh2, 0.f);
        v.w = fmaxf(v.w * sc3 + sh3, 0.f);
        o4[f] = v;
    }
}

extern "C" void kernel_launch(void* const* d_in, const int* in_sizes, int n_in,
                              void* d_out, int out_size, void* d_ws, size_t ws_size,
                              hipStream_t stream) {
    const float* feats  = (const float*)d_in[0];
    const int* in_idx   = (const int*)d_in[1];
    const int* out_idx  = (const int*)d_in[2];
    const float* weight = (const float*)d_in[3];
    const float* gamma  = (const float*)d_in[4];
    const float* beta   = (const float*)d_in[5];
    float* out = (float*)d_out;

    char* ws = (char*)d_ws;
    size_t off = 0;
    unsigned short* fb      = (unsigned short*)(ws + off); off += 38400000;
    unsigned short* wt      = (unsigned short*)(ws + off); off += 497664;
    unsigned short* contrib = (unsigned short*)(ws + off); off += (size_t)NPAIR * 96 * 2;
    int* counts             = (int*)(ws + off); off += 2400000;
    int* csr                = (int*)(ws + off); off += 2400016;
    int* cursor             = (int*)(ws + off); off += 2400016;
    int* bsum               = (int*)(ws + off); off += 4096;
    int* bsum_ex            = (int*)(ws + off); off += 4096;
    int* rank               = (int*)(ws + off); off += (size_t)NPAIR * 4;
    float* sums             = (float*)(ws + off); off += 768;

    hipMemsetAsync(counts, 0, (size_t)N_OUT * sizeof(int), stream);
    hipMemsetAsync(sums, 0, 192 * sizeof(float), stream);

    cvt_feats<<<9375, 256, 0, stream>>>(feats, fb);
    cvt_w<<<972, 256, 0, stream>>>(weight, wt);

    k_hist<<<(NPAIR + 255) / 256, 256, 0, stream>>>(out_idx, counts);
    k_bsum<<<586, 256, 0, stream>>>(counts, bsum);
    k_scan_bsum<<<1, 1024, 0, stream>>>(bsum, bsum_ex);
    k_scan_local<<<586, 256, 0, stream>>>(counts, bsum_ex, csr);
    hipMemcpyAsync(cursor, csr, (size_t)N_OUT * sizeof(int), hipMemcpyDeviceToDevice, stream);
    k_rank<<<(NPAIR + 255) / 256, 256, 0, stream>>>(out_idx, cursor, rank);

    contrib_k<<<dim3(2344, KOFF), 256, 0, stream>>>(fb, wt, in_idx, rank, contrib);

    reduce_bn<<<9375, 384, 0, stream>>>(contrib, csr, out, sums);
    bn_final<<<1, 128, 0, stream>>>(sums, gamma, beta);
    bn_apply<<<1008, 256, 0, stream>>>(out, sums);
}